// Round 4
// baseline (10.177 us; speedup 1.0000x reference)
//
#include <hip/hip_runtime.h>
#include <math.h>

// Problem constants (match reference.py)
#define DFOCK 2048
#define BATCH 256
#define ROWS  (2 * DFOCK)          // 4096
#define ELEMS (ROWS * BATCH)       // 1,048,576 floats per real/imag plane
#define NVEC8 (ELEMS / 8)          // 131,072 threads, 8 floats per plane each

// Native clang vector type: __builtin_nontemporal_* requires it (HIP float4
// is a struct and is rejected).
typedef float f32x4 __attribute__((ext_vector_type(4)));

// Diagonal phase rotation (see round-1 derivation):
//   n = row>>1, theta = pi*angle*n = 2*pi*(angle*n/2)
// Hardware v_sin_f32/v_cos_f32 take revolutions; reduce rev mod 1 in double.
__global__ __launch_bounds__(256)
void rotation_phase_kernel(const float* __restrict__ angle,
                           const float* __restrict__ xr,
                           const float* __restrict__ xi,
                           float* __restrict__ out) {
    const int tid = blockIdx.x * blockDim.x + threadIdx.x;
    if (tid >= NVEC8) return;

    const int e   = tid << 3;        // flat float index (8 per thread)
    const int row = e >> 8;          // e / BATCH (BATCH == 256); 8 floats never cross a row
    const int n   = row >> 1;        // Fock index

    const double ang = (double)angle[0];
    double rev = 0.5 * ang * (double)n;
    rev -= floor(rev);
    const float fr = (float)rev;     // [0,1)

    const float s = __builtin_amdgcn_sinf(fr);   // sin(2*pi*fr)
    const float c = __builtin_amdgcn_cosf(fr);   // cos(2*pi*fr)

    const f32x4* pr  = reinterpret_cast<const f32x4*>(xr + e);
    const f32x4* pi4 = reinterpret_cast<const f32x4*>(xi + e);
    f32x4 vr0 = __builtin_nontemporal_load(pr);
    f32x4 vr1 = __builtin_nontemporal_load(pr + 1);
    f32x4 vi0 = __builtin_nontemporal_load(pi4);
    f32x4 vi1 = __builtin_nontemporal_load(pi4 + 1);

    f32x4 or0 = c * vr0 - s * vi0;
    f32x4 or1 = c * vr1 - s * vi1;
    f32x4 oi0 = s * vr0 + c * vi0;
    f32x4 oi1 = s * vr1 + c * vi1;

    f32x4* qr = reinterpret_cast<f32x4*>(out + e);
    f32x4* qi = reinterpret_cast<f32x4*>(out + ELEMS + e);
    __builtin_nontemporal_store(or0, qr);
    __builtin_nontemporal_store(or1, qr + 1);
    __builtin_nontemporal_store(oi0, qi);
    __builtin_nontemporal_store(oi1, qi + 1);
}

extern "C" void kernel_launch(void* const* d_in, const int* in_sizes, int n_in,
                              void* d_out, int out_size, void* d_ws, size_t ws_size,
                              hipStream_t stream) {
    // Inputs per setup_inputs(): angle (1), a (D*D, unused), x_real (2D*B), x_imag (2D*B)
    const float* angle = (const float*)d_in[0];
    const float* xr    = (const float*)d_in[2];
    const float* xi    = (const float*)d_in[3];
    float* out         = (float*)d_out;

    const int threads = 256;
    const int blocks  = (NVEC8 + threads - 1) / threads;   // 512
    rotation_phase_kernel<<<blocks, threads, 0, stream>>>(angle, xr, xi, out);
}